// Round 5
// baseline (220.178 us; speedup 1.0000x reference)
//
#include <hip/hip_runtime.h>
#include <hip/hip_bf16.h>

// Problem constants (fixed by setup_inputs): B=4, D=32, H=512, W=512, K=16
#define B_ 4
#define D_ 32
#define H_ 512
#define W_ 512
#define K_ 16
#define N_ (H_ * W_)    // 262144 pixels per image
#define NQ_ (N_ / 4)    // 65536 float4-quads per image
#define NBLK_ 256       // attract blocks per image (256 blk * 256 thr * 4 px = N_)
#define EPAD 33         // sE row pad: bank=(k*33+d)%32 distinct for distinct k

// Workspace layout (float indices):
#define WS_SUM  0      // [64]  sum[b][k]
#define WS_CNT  64     // [64]  cnt[b][k]
#define WS_E2   128    // [64]  |E_k|^2
#define WS_LAB  192    // [64]  label at center (int32 reinterpret)
#define WS_E    264    // [2048] E[b][k][d]
#define WS_PART 4096   // [B*NBLK*32] per-block partials: [b][blk][k]=sum, [16+k]=cnt

typedef float vfloat4 __attribute__((ext_vector_type(4)));
typedef int vint4 __attribute__((ext_vector_type(4)));

__device__ inline vfloat4 nt_load_f4(const float* p) {
  return __builtin_nontemporal_load((const vfloat4*)p);
}
__device__ inline vint4 nt_load_i4(const int* p) {
  return __builtin_nontemporal_load((const vint4*)p);
}

__global__ __launch_bounds__(64) void setup_kernel(
    const float* __restrict__ outp, const int* __restrict__ target,
    const int* __restrict__ centers, float* __restrict__ ws) {
  const int b = blockIdx.x, k = blockIdx.y;
  const int lane = threadIdx.x;
  const int cy = centers[(b * K_ + k) * 2 + 0];
  const int cx = centers[(b * K_ + k) * 2 + 1];
  float v = 0.0f;
  if (lane < D_) {
    v = outp[(((size_t)b * D_ + lane) * H_ + cy) * W_ + cx];
    ws[WS_E + (b * K_ + k) * D_ + lane] = v;
  }
  float s = v * v;
  for (int off = 32; off > 0; off >>= 1) s += __shfl_xor(s, off, 64);
  if (lane == 0) {
    ws[WS_E2 + b * K_ + k] = s;
    ((int*)ws)[WS_LAB + b * K_ + k] = target[(size_t)b * N_ + cy * W_ + cx];
  }
}

__global__ __launch_bounds__(256, 4) void attract_kernel(
    const float* __restrict__ outp, const int* __restrict__ target,
    float* __restrict__ ws) {
  const int b = blockIdx.y;
  const int tid = threadIdx.x;
  __shared__ float sE[K_ * EPAD];
  __shared__ float se2[K_];
  __shared__ int slab[K_];
  __shared__ float bs[K_];
  __shared__ float bc[K_];

  if (tid < 128) {
    const vfloat4 v = *(const vfloat4*)(ws + WS_E + b * (K_ * D_) + tid * 4);
    const int k = tid >> 3, d = (tid & 7) * 4;
    sE[k * EPAD + d + 0] = v.x;
    sE[k * EPAD + d + 1] = v.y;
    sE[k * EPAD + d + 2] = v.z;
    sE[k * EPAD + d + 3] = v.w;
  }
  if (tid < K_) {
    se2[tid] = ws[WS_E2 + b * K_ + tid];
    slab[tid] = ((const int*)ws)[WS_LAB + b * K_ + tid];
    bs[tid] = 0.0f;
    bc[tid] = 0.0f;
  }
  __syncthreads();

  const int q = blockIdx.x * 256 + tid;  // [0, NQ_)
  const float* xb = outp + (size_t)b * D_ * N_;
  const vint4 lab4 = nt_load_i4(target + (size_t)b * N_ + 4 * q);
  const int labv[4] = {lab4.x, lab4.y, lab4.z, lab4.w};

  int kf[4], nm[4];
#pragma unroll
  for (int j = 0; j < 4; ++j) { kf[j] = 0; nm[j] = 0; }
#pragma unroll
  for (int k = 0; k < K_; ++k) {
    const int lk = slab[k];
#pragma unroll
    for (int j = 0; j < 4; ++j) {
      if (labv[j] == lk) { if (nm[j] == 0) kf[j] = k; nm[j]++; }
    }
  }

  // Fast-path detection: every pixel matches exactly one center, each
  // thread's 4 pixels share it, and it is uniform per half-wave.
  const int lane = tid & 63;
  const bool thread_ok =
      (nm[0] == 1) & (nm[1] == 1) & (nm[2] == 1) & (nm[3] == 1) &
      (kf[1] == kf[0]) & (kf[2] == kf[0]) & (kf[3] == kf[0]);
  const int kA = __builtin_amdgcn_readfirstlane(kf[0]);
  const int kB = __shfl(kf[0], 32, 64);
  const bool low = lane < 32;
  const bool half_ok = kf[0] == (low ? kA : kB);
  const bool fast = __all(thread_ok & half_ok);

  if (fast) {
    // E rows via wave-uniform (SGPR) loads; no LDS in the hot loop.
    const float* __restrict__ eA = ws + WS_E + (b * K_ + kA) * D_;
    const float* __restrict__ eB = ws + WS_E + (b * K_ + __builtin_amdgcn_readfirstlane(kB)) * D_;
    float dot[4] = {0.f, 0.f, 0.f, 0.f};
    float x2[4] = {0.f, 0.f, 0.f, 0.f};
#pragma unroll 8
    for (int d = 0; d < D_; ++d) {
      const vfloat4 x = nt_load_f4(xb + (size_t)d * N_ + 4 * q);
      const float e = low ? eA[d] : eB[d];  // s_load pair + cndmask
      dot[0] = fmaf(x.x, e, dot[0]);
      x2[0] = fmaf(x.x, x.x, x2[0]);
      dot[1] = fmaf(x.y, e, dot[1]);
      x2[1] = fmaf(x.y, x.y, x2[1]);
      dot[2] = fmaf(x.z, e, dot[2]);
      x2[2] = fmaf(x.z, x.z, x2[2]);
      dot[3] = fmaf(x.w, e, dot[3]);
      x2[3] = fmaf(x.w, x.w, x2[3]);
    }
    const float e2k = se2[kf[0]];
    float hq = 0.0f;
#pragma unroll
    for (int j = 0; j < 4; ++j) {
      const float d2 = x2[j] + e2k - 2.0f * dot[j];
      hq += fmaxf(sqrtf(fmaxf(d2, 0.0f)) - 0.1f, 0.0f);  // DELTA_A=0.1
    }
    for (int off = 16; off > 0; off >>= 1) hq += __shfl_xor(hq, off, 64);
    if ((lane & 31) == 0) {
      atomicAdd(&bs[kf[0]], hq);
      atomicAdd(&bc[kf[0]], 128.0f);  // 32 lanes * 4 px, all counted
    }
  } else {
    // Generic path (any label layout, duplicate-label centers).
    float dot[4] = {0.f, 0.f, 0.f, 0.f};
    float x2[4] = {0.f, 0.f, 0.f, 0.f};
#pragma unroll 8
    for (int d = 0; d < D_; ++d) {
      const vfloat4 x = nt_load_f4(xb + (size_t)d * N_ + 4 * q);
      const float xs[4] = {x.x, x.y, x.z, x.w};
#pragma unroll
      for (int j = 0; j < 4; ++j) {
        const float e = sE[kf[j] * EPAD + d];
        dot[j] = fmaf(xs[j], e, dot[j]);
        x2[j] = fmaf(xs[j], xs[j], x2[j]);
      }
    }
#pragma unroll
    for (int j = 0; j < 4; ++j) {
      if (nm[j] > 0) {
        const float d2 = x2[j] + se2[kf[j]] - 2.0f * dot[j];
        atomicAdd(&bs[kf[j]], fmaxf(sqrtf(fmaxf(d2, 0.0f)) - 0.1f, 0.0f));
        atomicAdd(&bc[kf[j]], 1.0f);
      }
    }
    const bool extra = (nm[0] > 1) | (nm[1] > 1) | (nm[2] > 1) | (nm[3] > 1);
    if (__any(extra)) {
      for (int k = 0; k < K_; ++k) {
        bool need[4]; bool anyn = false;
#pragma unroll
        for (int j = 0; j < 4; ++j) {
          need[j] = (nm[j] > 1) && (labv[j] == slab[k]) && (k != kf[j]);
          anyn |= need[j];
        }
        if (__any(anyn)) {
          float dt[4] = {0.f, 0.f, 0.f, 0.f};
          for (int d = 0; d < D_; ++d) {
            const vfloat4 x = nt_load_f4(xb + (size_t)d * N_ + 4 * q);
            const float e = sE[k * EPAD + d];
            dt[0] = fmaf(x.x, e, dt[0]);
            dt[1] = fmaf(x.y, e, dt[1]);
            dt[2] = fmaf(x.z, e, dt[2]);
            dt[3] = fmaf(x.w, e, dt[3]);
          }
#pragma unroll
          for (int j = 0; j < 4; ++j) {
            if (need[j]) {
              const float d2 = x2[j] + se2[k] - 2.0f * dt[j];
              atomicAdd(&bs[k], fmaxf(sqrtf(fmaxf(d2, 0.0f)) - 0.1f, 0.0f));
              atomicAdd(&bc[k], 1.0f);
            }
          }
        }
      }
    }
  }
  __syncthreads();

  if (tid < 2 * K_) {
    float* p = ws + WS_PART + ((size_t)b * NBLK_ + blockIdx.x) * (2 * K_);
    p[tid] = (tid < K_) ? bs[tid] : bc[tid - K_];
  }
}

__global__ __launch_bounds__(256) void final_kernel(const float* __restrict__ ws,
                                                    float* __restrict__ out) {
  __shared__ float sE[B_ * K_ * D_];
  __shared__ float sred[256];
  __shared__ float scred[256];
  __shared__ float ssum[B_ * K_];
  __shared__ float scnt[B_ * K_];
  __shared__ float srep[B_];
  __shared__ float sreg[B_];
  __shared__ float ssa[B_];
  const int tid = threadIdx.x;

  // Phase 0: reduce per-block attract partials. pair p = tid>>2, sub = tid&3.
  {
    const int p = tid >> 2, sub = tid & 3;
    const int bb = p >> 4, kk = p & 15;
    const float* base = ws + WS_PART + (size_t)bb * NBLK_ * (2 * K_);
    float s = 0.0f, c = 0.0f;
    for (int i = sub; i < NBLK_; i += 4) {
      s += base[i * (2 * K_) + kk];
      c += base[i * (2 * K_) + K_ + kk];
    }
    sred[tid] = s;
    scred[tid] = c;
  }
  for (int i = tid; i < B_ * K_ * D_; i += 256) sE[i] = ws[WS_E + i];
  __syncthreads();
  if (tid < B_ * K_) {
    ssum[tid] = sred[tid * 4] + sred[tid * 4 + 1] + sred[tid * 4 + 2] + sred[tid * 4 + 3];
    scnt[tid] = scred[tid * 4] + scred[tid * 4 + 1] + scred[tid * 4 + 2] + scred[tid * 4 + 3];
  }
  __syncthreads();

  // Repulse: 256 pairs per image, tree-reduce per b.
  const int i = tid >> 4, j = tid & 15;
  for (int b = 0; b < B_; ++b) {
    float dotv = 0.0f;
#pragma unroll 8
    for (int d = 0; d < D_; ++d)
      dotv = fmaf(sE[(b * K_ + i) * D_ + d], sE[(b * K_ + j) * D_ + d], dotv);
    const float d2 = ws[WS_E2 + b * K_ + i] + ws[WS_E2 + b * K_ + j] - 2.0f * dotv;
    sred[tid] = fmaxf(1.0f - sqrtf(fmaxf(d2, 0.0f)), 0.0f);  // DELTA_R=1.0
    __syncthreads();
    for (int s = 128; s > 0; s >>= 1) {
      if (tid < s) sred[tid] += sred[tid + s];
      __syncthreads();
    }
    if (tid == 0) srep[b] = sred[0] - (float)K_;
    __syncthreads();
  }

  // Reg: sqrt(|E|^2) summed per b.
  sred[tid] = (tid < B_ * K_) ? sqrtf(fmaxf(ws[WS_E2 + tid], 0.0f)) : 0.0f;
  __syncthreads();
  if (tid < B_) {
    float s = 0.0f;
    for (int k = 0; k < K_; ++k) s += sred[tid * K_ + k];
    sreg[tid] = s;
  }

  // Attract per-b sums from shared.
  if (tid < B_ * K_) {
    float v = ssum[tid] / fmaxf(scnt[tid] - 1.0f, 1.0f);
    for (int off = 1; off < K_; off <<= 1) v += __shfl_xor(v, off, 64);
    if ((tid & 15) == 0) ssa[tid >> 4] = v;
  }
  __syncthreads();

  if (tid == 0) {
    float att = 0.0f, rep = 0.0f, reg = 0.0f;
    for (int b = 0; b < B_; ++b) {
      att = (att + ssa[b]) / (float)K_;
      rep = (rep + srep[b]) / (float)(K_ * (K_ - 1));
      reg = (reg + sreg[b]) / (float)K_;
    }
    out[0] = att + rep + 0.001f * reg;  // ALPHA=BETA=1, GAMMA=0.001
    out[1] = att;
    out[2] = rep;
  }
}

extern "C" void kernel_launch(void* const* d_in, const int* in_sizes, int n_in,
                              void* d_out, int out_size, void* d_ws, size_t ws_size,
                              hipStream_t stream) {
  const float* outp = (const float*)d_in[0];
  const int* target = (const int*)d_in[1];
  const int* centers = (const int*)d_in[2];
  float* ws = (float*)d_ws;
  float* out = (float*)d_out;

  setup_kernel<<<dim3(B_, K_), 64, 0, stream>>>(outp, target, centers, ws);
  attract_kernel<<<dim3(NBLK_, B_), 256, 0, stream>>>(outp, target, ws);
  final_kernel<<<1, 256, 0, stream>>>(ws, out);
}

// Round 6
// 216.115 us; speedup vs baseline: 1.0188x; 1.0188x over previous
//
#include <hip/hip_runtime.h>
#include <hip/hip_bf16.h>

// Problem constants (fixed by setup_inputs): B=4, D=32, H=512, W=512, K=16
#define B_ 4
#define D_ 32
#define H_ 512
#define W_ 512
#define K_ 16
#define N_ (H_ * W_)    // 262144 pixels per image
#define NQ_ (N_ / 4)    // 65536 float4-quads per image
#define NBLK_ 256       // attract blocks per image (256 blk * 256 thr * 4 px = N_)
#define EPAD 33         // sE row pad: bank=(k*33+d)%32 distinct for distinct k

// Workspace layout (float indices):
#define WS_PART 0      // [B*NBLK*32] per-block partials: [b][blk][k]=sum, [16+k]=cnt

typedef float vfloat4 __attribute__((ext_vector_type(4)));
typedef int vint4 __attribute__((ext_vector_type(4)));

__device__ inline vfloat4 nt_load_f4(const float* p) {
  return __builtin_nontemporal_load((const vfloat4*)p);
}
__device__ inline vint4 nt_load_i4(const int* p) {
  return __builtin_nontemporal_load((const vint4*)p);
}

// Fused: each block gathers E itself (no setup kernel, no cross-kernel dep).
__global__ __launch_bounds__(256) void attract_kernel(
    const float* __restrict__ outp, const int* __restrict__ target,
    const int* __restrict__ centers, float* __restrict__ ws) {
  const int b = blockIdx.y;
  const int tid = threadIdx.x;
  __shared__ float sE[K_ * EPAD];
  __shared__ float se2[K_];
  __shared__ int slab[K_];
  __shared__ float bs[K_];
  __shared__ float bc[K_];

  // Self-gather E[k][d] = out[b, d, cy_k, cx_k]: 512 independent loads.
  for (int i = tid; i < K_ * D_; i += 256) {
    const int k = i >> 5, d = i & 31;
    const int cy = centers[(b * K_ + k) * 2 + 0];
    const int cx = centers[(b * K_ + k) * 2 + 1];
    sE[k * EPAD + d] = outp[(((size_t)b * D_ + d) * H_ + cy) * W_ + cx];
  }
  if (tid < K_) {
    const int cy = centers[(b * K_ + tid) * 2 + 0];
    const int cx = centers[(b * K_ + tid) * 2 + 1];
    slab[tid] = target[(size_t)b * N_ + cy * W_ + cx];
    bs[tid] = 0.0f;
    bc[tid] = 0.0f;
  }
  __syncthreads();
  if (tid < K_) {
    float s = 0.0f;
#pragma unroll
    for (int d = 0; d < D_; ++d) s = fmaf(sE[tid * EPAD + d], sE[tid * EPAD + d], s);
    se2[tid] = s;
  }
  __syncthreads();

  // One float4-quad of pixels per thread.
  const int q = blockIdx.x * 256 + tid;  // [0, NQ_)
  const float* xb = outp + (size_t)b * D_ * N_;
  const vint4 lab4 = nt_load_i4(target + (size_t)b * N_ + 4 * q);
  const int labv[4] = {lab4.x, lab4.y, lab4.z, lab4.w};

  int kf[4], nm[4];
#pragma unroll
  for (int j = 0; j < 4; ++j) { kf[j] = 0; nm[j] = 0; }
#pragma unroll
  for (int k = 0; k < K_; ++k) {
    const int lk = slab[k];
#pragma unroll
    for (int j = 0; j < 4; ++j) {
      if (labv[j] == lk) { if (nm[j] == 0) kf[j] = k; nm[j]++; }
    }
  }

  float dot[4] = {0.f, 0.f, 0.f, 0.f};
  float x2[4] = {0.f, 0.f, 0.f, 0.f};
#pragma unroll 16
  for (int d = 0; d < D_; ++d) {
    const vfloat4 x = nt_load_f4(xb + (size_t)d * N_ + 4 * q);
    const float xs[4] = {x.x, x.y, x.z, x.w};
#pragma unroll
    for (int j = 0; j < 4; ++j) {
      const float e = sE[kf[j] * EPAD + d];  // half-wave-uniform -> broadcast (free)
      dot[j] = fmaf(xs[j], e, dot[j]);
      x2[j] = fmaf(xs[j], xs[j], x2[j]);
    }
  }

  float hv[4];
#pragma unroll
  for (int j = 0; j < 4; ++j) {
    const float d2 = x2[j] + se2[kf[j]] - 2.0f * dot[j];
    const float h = fmaxf(sqrtf(fmaxf(d2, 0.0f)) - 0.1f, 0.0f);  // DELTA_A=0.1
    hv[j] = (nm[j] > 0) ? h : 0.0f;
  }
  const bool same = (kf[0] == kf[1]) & (kf[1] == kf[2]) & (kf[2] == kf[3]);
  if (same) {  // common case: a thread's 4 consecutive pixels share a label
    const float cs = (float)((nm[0] > 0) + (nm[1] > 0) + (nm[2] > 0) + (nm[3] > 0));
    if (cs > 0.0f) {
      atomicAdd(&bs[kf[0]], hv[0] + hv[1] + hv[2] + hv[3]);
      atomicAdd(&bc[kf[0]], cs);
    }
  } else {
#pragma unroll
    for (int j = 0; j < 4; ++j) {
      if (nm[j] > 0) {
        atomicAdd(&bs[kf[j]], hv[j]);
        atomicAdd(&bc[kf[j]], 1.0f);
      }
    }
  }

  // Rare general case: duplicate-label centers (never taken on this input).
  const bool extra = (nm[0] > 1) | (nm[1] > 1) | (nm[2] > 1) | (nm[3] > 1);
  if (__any(extra)) {
    for (int k = 0; k < K_; ++k) {
      bool need[4]; bool anyn = false;
#pragma unroll
      for (int j = 0; j < 4; ++j) {
        need[j] = (nm[j] > 1) && (labv[j] == slab[k]) && (k != kf[j]);
        anyn |= need[j];
      }
      if (__any(anyn)) {
        float dt[4] = {0.f, 0.f, 0.f, 0.f};
        for (int d = 0; d < D_; ++d) {
          const vfloat4 x = nt_load_f4(xb + (size_t)d * N_ + 4 * q);
          const float e = sE[k * EPAD + d];
          dt[0] = fmaf(x.x, e, dt[0]);
          dt[1] = fmaf(x.y, e, dt[1]);
          dt[2] = fmaf(x.z, e, dt[2]);
          dt[3] = fmaf(x.w, e, dt[3]);
        }
#pragma unroll
        for (int j = 0; j < 4; ++j) {
          if (need[j]) {
            const float d2 = x2[j] + se2[k] - 2.0f * dt[j];
            atomicAdd(&bs[k], fmaxf(sqrtf(fmaxf(d2, 0.0f)) - 0.1f, 0.0f));
            atomicAdd(&bc[k], 1.0f);
          }
        }
      }
    }
  }
  __syncthreads();

  if (tid < 2 * K_) {
    float* p = ws + WS_PART + ((size_t)b * NBLK_ + blockIdx.x) * (2 * K_);
    p[tid] = (tid < K_) ? bs[tid] : bc[tid - K_];
  }
}

__global__ __launch_bounds__(256) void final_kernel(
    const float* __restrict__ outp, const int* __restrict__ centers,
    const float* __restrict__ ws, float* __restrict__ out) {
  __shared__ float sE[B_ * K_ * D_];
  __shared__ float se2[B_ * K_];
  __shared__ float sred[256];
  __shared__ float scred[256];
  __shared__ float ssum[B_ * K_];
  __shared__ float scnt[B_ * K_];
  __shared__ float srep[B_];
  __shared__ float sreg[B_];
  __shared__ float ssa[B_];
  const int tid = threadIdx.x;

  // Gather E directly (L2-warm from attract): 2048 elems / 256 threads.
  for (int i = tid; i < B_ * K_ * D_; i += 256) {
    const int bk = i >> 5, d = i & 31;
    const int b = bk >> 4, k = bk & 15;
    const int cy = centers[(b * K_ + k) * 2 + 0];
    const int cx = centers[(b * K_ + k) * 2 + 1];
    sE[i] = outp[(((size_t)b * D_ + d) * H_ + cy) * W_ + cx];
  }

  // Phase 0: reduce per-block attract partials. pair p = tid>>2, sub = tid&3.
  {
    const int p = tid >> 2, sub = tid & 3;
    const int bb = p >> 4, kk = p & 15;
    const float* base = ws + WS_PART + (size_t)bb * NBLK_ * (2 * K_);
    float s = 0.0f, c = 0.0f;
    for (int i = sub; i < NBLK_; i += 4) {
      s += base[i * (2 * K_) + kk];
      c += base[i * (2 * K_) + K_ + kk];
    }
    sred[tid] = s;
    scred[tid] = c;
  }
  __syncthreads();
  if (tid < B_ * K_) {
    ssum[tid] = sred[tid * 4] + sred[tid * 4 + 1] + sred[tid * 4 + 2] + sred[tid * 4 + 3];
    scnt[tid] = scred[tid * 4] + scred[tid * 4 + 1] + scred[tid * 4 + 2] + scred[tid * 4 + 3];
    float s = 0.0f;
#pragma unroll
    for (int d = 0; d < D_; ++d) s = fmaf(sE[tid * D_ + d], sE[tid * D_ + d], s);
    se2[tid] = s;
  }
  __syncthreads();

  // Repulse: 256 pairs per image, tree-reduce per b.
  const int i = tid >> 4, j = tid & 15;
  for (int b = 0; b < B_; ++b) {
    float dotv = 0.0f;
#pragma unroll 8
    for (int d = 0; d < D_; ++d)
      dotv = fmaf(sE[(b * K_ + i) * D_ + d], sE[(b * K_ + j) * D_ + d], dotv);
    const float d2 = se2[b * K_ + i] + se2[b * K_ + j] - 2.0f * dotv;
    sred[tid] = fmaxf(1.0f - sqrtf(fmaxf(d2, 0.0f)), 0.0f);  // DELTA_R=1.0
    __syncthreads();
    for (int s = 128; s > 0; s >>= 1) {
      if (tid < s) sred[tid] += sred[tid + s];
      __syncthreads();
    }
    if (tid == 0) srep[b] = sred[0] - (float)K_;
    __syncthreads();
  }

  // Reg: sqrt(|E|^2) summed per b.
  sred[tid] = (tid < B_ * K_) ? sqrtf(fmaxf(se2[tid], 0.0f)) : 0.0f;
  __syncthreads();
  if (tid < B_) {
    float s = 0.0f;
    for (int k = 0; k < K_; ++k) s += sred[tid * K_ + k];
    sreg[tid] = s;
  }

  // Attract per-b sums from shared.
  if (tid < B_ * K_) {
    float v = ssum[tid] / fmaxf(scnt[tid] - 1.0f, 1.0f);
    for (int off = 1; off < K_; off <<= 1) v += __shfl_xor(v, off, 64);
    if ((tid & 15) == 0) ssa[tid >> 4] = v;
  }
  __syncthreads();

  if (tid == 0) {
    float att = 0.0f, rep = 0.0f, reg = 0.0f;
    for (int b = 0; b < B_; ++b) {
      att = (att + ssa[b]) / (float)K_;
      rep = (rep + srep[b]) / (float)(K_ * (K_ - 1));
      reg = (reg + sreg[b]) / (float)K_;
    }
    out[0] = att + rep + 0.001f * reg;  // ALPHA=BETA=1, GAMMA=0.001
    out[1] = att;
    out[2] = rep;
  }
}

extern "C" void kernel_launch(void* const* d_in, const int* in_sizes, int n_in,
                              void* d_out, int out_size, void* d_ws, size_t ws_size,
                              hipStream_t stream) {
  const float* outp = (const float*)d_in[0];
  const int* target = (const int*)d_in[1];
  const int* centers = (const int*)d_in[2];
  float* ws = (float*)d_ws;
  float* out = (float*)d_out;

  attract_kernel<<<dim3(NBLK_, B_), 256, 0, stream>>>(outp, target, centers, ws);
  final_kernel<<<1, 256, 0, stream>>>(outp, centers, ws, out);
}

// Round 7
// 206.583 us; speedup vs baseline: 1.0658x; 1.0461x over previous
//
#include <hip/hip_runtime.h>
#include <hip/hip_bf16.h>

// Problem constants (fixed by setup_inputs): B=4, D=32, H=512, W=512, K=16
#define B_ 4
#define D_ 32
#define H_ 512
#define W_ 512
#define K_ 16
#define N_ (H_ * W_)    // 262144 pixels per image
#define NO8_ (N_ / 8)   // 32768 8-pixel groups per image
#define NB2_ 128        // attract blocks per image (128 blk * 256 thr * 8 px = N_)
#define EPAD 33         // sE row pad: bank=(k*33+d)%32 distinct for distinct k

// Workspace layout (float indices):
#define WS_SUM  0      // [64]  (unused placeholder)
#define WS_CNT  64     // [64]
#define WS_E2   128    // [64]  |E_k|^2
#define WS_LAB  192    // [64]  label at center (int32 reinterpret)
#define WS_E    264    // [2048] E[b][k][d]
#define WS_PART 4096   // [B*NB2*32] per-block partials: [b][blk][k]=sum, [16+k]=cnt

typedef float vfloat4 __attribute__((ext_vector_type(4)));
typedef int vint4 __attribute__((ext_vector_type(4)));

__device__ inline vfloat4 nt_load_f4(const float* p) {
  return __builtin_nontemporal_load((const vfloat4*)p);
}
__device__ inline vint4 nt_load_i4(const int* p) {
  return __builtin_nontemporal_load((const vint4*)p);
}

__global__ __launch_bounds__(64) void setup_kernel(
    const float* __restrict__ outp, const int* __restrict__ target,
    const int* __restrict__ centers, float* __restrict__ ws) {
  const int b = blockIdx.x, k = blockIdx.y;
  const int lane = threadIdx.x;
  const int cy = centers[(b * K_ + k) * 2 + 0];
  const int cx = centers[(b * K_ + k) * 2 + 1];
  float v = 0.0f;
  if (lane < D_) {
    v = outp[(((size_t)b * D_ + lane) * H_ + cy) * W_ + cx];
    ws[WS_E + (b * K_ + k) * D_ + lane] = v;
  }
  float s = v * v;
  for (int off = 32; off > 0; off >>= 1) s += __shfl_xor(s, off, 64);
  if (lane == 0) {
    ws[WS_E2 + b * K_ + k] = s;
    ((int*)ws)[WS_LAB + b * K_ + k] = target[(size_t)b * N_ + cy * W_ + cx];
  }
}

__global__ __launch_bounds__(256) void attract_kernel(
    const float* __restrict__ outp, const int* __restrict__ target,
    float* __restrict__ ws) {
  const int b = blockIdx.y;
  const int tid = threadIdx.x;
  __shared__ float sE[K_ * EPAD];
  __shared__ float se2[K_];
  __shared__ int slab[K_];
  __shared__ float bs[K_];
  __shared__ float bc[K_];

  // Stage E from ws (linear float4 reads).
  if (tid < 128) {
    const vfloat4 v = *(const vfloat4*)(ws + WS_E + b * (K_ * D_) + tid * 4);
    const int k = tid >> 3, d = (tid & 7) * 4;
    sE[k * EPAD + d + 0] = v.x;
    sE[k * EPAD + d + 1] = v.y;
    sE[k * EPAD + d + 2] = v.z;
    sE[k * EPAD + d + 3] = v.w;
  }
  if (tid < K_) {
    se2[tid] = ws[WS_E2 + b * K_ + tid];
    slab[tid] = ((const int*)ws)[WS_LAB + b * K_ + tid];
    bs[tid] = 0.0f;
    bc[tid] = 0.0f;
  }
  __syncthreads();

  // 8 consecutive pixels per thread.
  const int g = blockIdx.x * 256 + tid;  // [0, NO8_)
  const float* xb = outp + (size_t)b * D_ * N_;
  const int* tb = target + (size_t)b * N_;
  const vint4 la = nt_load_i4(tb + 8 * g);
  const vint4 lb = nt_load_i4(tb + 8 * g + 4);
  const int lab[8] = {la.x, la.y, la.z, la.w, lb.x, lb.y, lb.z, lb.w};

  bool alleq = true;
#pragma unroll
  for (int j = 1; j < 8; ++j) alleq &= (lab[j] == lab[0]);

  int kf0 = 0, nm0 = 0;
  if (alleq) {
#pragma unroll
    for (int k = 0; k < K_; ++k) {
      if (lab[0] == slab[k]) { if (nm0 == 0) kf0 = k; nm0++; }
    }
  }
  const int lane = tid & 63;
  const int kg = __shfl(kf0, lane & ~15, 64);  // quarter-wave leader's center
  const bool ok = alleq && (nm0 == 1) && (kf0 == kg);

  if (__all(ok)) {
    // Fast path: one LDS read per d; diff^2 accumulation (== x2+e2-2dot, >=0).
    float acc[8] = {0.f, 0.f, 0.f, 0.f, 0.f, 0.f, 0.f, 0.f};
#pragma unroll 8
    for (int d = 0; d < D_; ++d) {
      const vfloat4 xa = nt_load_f4(xb + (size_t)d * N_ + 8 * g);
      const vfloat4 xc = nt_load_f4(xb + (size_t)d * N_ + 8 * g + 4);
      const float e = sE[kf0 * EPAD + d];
      const float v0 = xa.x - e, v1 = xa.y - e, v2 = xa.z - e, v3 = xa.w - e;
      const float v4 = xc.x - e, v5 = xc.y - e, v6 = xc.z - e, v7 = xc.w - e;
      acc[0] = fmaf(v0, v0, acc[0]);
      acc[1] = fmaf(v1, v1, acc[1]);
      acc[2] = fmaf(v2, v2, acc[2]);
      acc[3] = fmaf(v3, v3, acc[3]);
      acc[4] = fmaf(v4, v4, acc[4]);
      acc[5] = fmaf(v5, v5, acc[5]);
      acc[6] = fmaf(v6, v6, acc[6]);
      acc[7] = fmaf(v7, v7, acc[7]);
    }
    float hq = 0.0f;
#pragma unroll
    for (int j = 0; j < 8; ++j)
      hq += fmaxf(sqrtf(acc[j]) - 0.1f, 0.0f);  // DELTA_A=0.1
    // Quarter-wave (16-lane) butterfly; kf0 uniform within each group.
    hq += __shfl_xor(hq, 1, 64);
    hq += __shfl_xor(hq, 2, 64);
    hq += __shfl_xor(hq, 4, 64);
    hq += __shfl_xor(hq, 8, 64);
    if ((lane & 15) == 0) {
      atomicAdd(&bs[kf0], hq);
      atomicAdd(&bc[kf0], 128.0f);  // 16 lanes * 8 px
    }
  } else {
    // Generic path: per-pixel center matching (any layout, duplicates).
    int kf[8], nm[8];
#pragma unroll
    for (int j = 0; j < 8; ++j) { kf[j] = 0; nm[j] = 0; }
#pragma unroll
    for (int k = 0; k < K_; ++k) {
      const int lk = slab[k];
#pragma unroll
      for (int j = 0; j < 8; ++j) {
        if (lab[j] == lk) { if (nm[j] == 0) kf[j] = k; nm[j]++; }
      }
    }
    float dot[8], x2[8];
#pragma unroll
    for (int j = 0; j < 8; ++j) { dot[j] = 0.f; x2[j] = 0.f; }
#pragma unroll 4
    for (int d = 0; d < D_; ++d) {
      const vfloat4 xa = nt_load_f4(xb + (size_t)d * N_ + 8 * g);
      const vfloat4 xc = nt_load_f4(xb + (size_t)d * N_ + 8 * g + 4);
      const float xs[8] = {xa.x, xa.y, xa.z, xa.w, xc.x, xc.y, xc.z, xc.w};
#pragma unroll
      for (int j = 0; j < 8; ++j) {
        const float e = sE[kf[j] * EPAD + d];
        dot[j] = fmaf(xs[j], e, dot[j]);
        x2[j] = fmaf(xs[j], xs[j], x2[j]);
      }
    }
#pragma unroll
    for (int j = 0; j < 8; ++j) {
      if (nm[j] > 0) {
        const float d2 = x2[j] + se2[kf[j]] - 2.0f * dot[j];
        atomicAdd(&bs[kf[j]], fmaxf(sqrtf(fmaxf(d2, 0.0f)) - 0.1f, 0.0f));
        atomicAdd(&bc[kf[j]], 1.0f);
      }
    }
    // Duplicate-label centers: hinge against every extra matching center.
    bool anyextra = false;
#pragma unroll
    for (int j = 0; j < 8; ++j) anyextra |= (nm[j] > 1);
    if (__any(anyextra)) {
      for (int k = 0; k < K_; ++k) {
        bool need[8]; bool anyn = false;
#pragma unroll
        for (int j = 0; j < 8; ++j) {
          need[j] = (nm[j] > 1) && (lab[j] == slab[k]) && (k != kf[j]);
          anyn |= need[j];
        }
        if (__any(anyn)) {
          float dt[8];
#pragma unroll
          for (int j = 0; j < 8; ++j) dt[j] = 0.f;
          for (int d = 0; d < D_; ++d) {
            const vfloat4 xa = nt_load_f4(xb + (size_t)d * N_ + 8 * g);
            const vfloat4 xc = nt_load_f4(xb + (size_t)d * N_ + 8 * g + 4);
            const float xs[8] = {xa.x, xa.y, xa.z, xa.w, xc.x, xc.y, xc.z, xc.w};
            const float e = sE[k * EPAD + d];
#pragma unroll
            for (int j = 0; j < 8; ++j) dt[j] = fmaf(xs[j], e, dt[j]);
          }
#pragma unroll
          for (int j = 0; j < 8; ++j) {
            if (need[j]) {
              const float d2 = x2[j] + se2[k] - 2.0f * dt[j];
              atomicAdd(&bs[k], fmaxf(sqrtf(fmaxf(d2, 0.0f)) - 0.1f, 0.0f));
              atomicAdd(&bc[k], 1.0f);
            }
          }
        }
      }
    }
  }
  __syncthreads();

  if (tid < 2 * K_) {
    float* p = ws + WS_PART + ((size_t)b * NB2_ + blockIdx.x) * (2 * K_);
    p[tid] = (tid < K_) ? bs[tid] : bc[tid - K_];
  }
}

__global__ __launch_bounds__(256) void final_kernel(const float* __restrict__ ws,
                                                    float* __restrict__ out) {
  __shared__ float sE[B_ * K_ * D_];
  __shared__ float sred[256];
  __shared__ float scred[256];
  __shared__ float ssum[B_ * K_];
  __shared__ float scnt[B_ * K_];
  __shared__ float srep[B_];
  __shared__ float sreg[B_];
  __shared__ float ssa[B_];
  const int tid = threadIdx.x;

  // Phase 0: reduce per-block attract partials. pair p = tid>>2, sub = tid&3.
  {
    const int p = tid >> 2, sub = tid & 3;
    const int bb = p >> 4, kk = p & 15;
    const float* base = ws + WS_PART + (size_t)bb * NB2_ * (2 * K_);
    float s = 0.0f, c = 0.0f;
    for (int i = sub; i < NB2_; i += 4) {
      s += base[i * (2 * K_) + kk];
      c += base[i * (2 * K_) + K_ + kk];
    }
    sred[tid] = s;
    scred[tid] = c;
  }
  for (int i = tid; i < B_ * K_ * D_; i += 256) sE[i] = ws[WS_E + i];
  __syncthreads();
  if (tid < B_ * K_) {
    ssum[tid] = sred[tid * 4] + sred[tid * 4 + 1] + sred[tid * 4 + 2] + sred[tid * 4 + 3];
    scnt[tid] = scred[tid * 4] + scred[tid * 4 + 1] + scred[tid * 4 + 2] + scred[tid * 4 + 3];
  }
  __syncthreads();

  // Repulse: 256 pairs per image, tree-reduce per b.
  const int i = tid >> 4, j = tid & 15;
  for (int b = 0; b < B_; ++b) {
    float dotv = 0.0f;
#pragma unroll 8
    for (int d = 0; d < D_; ++d)
      dotv = fmaf(sE[(b * K_ + i) * D_ + d], sE[(b * K_ + j) * D_ + d], dotv);
    const float d2 = ws[WS_E2 + b * K_ + i] + ws[WS_E2 + b * K_ + j] - 2.0f * dotv;
    sred[tid] = fmaxf(1.0f - sqrtf(fmaxf(d2, 0.0f)), 0.0f);  // DELTA_R=1.0
    __syncthreads();
    for (int s = 128; s > 0; s >>= 1) {
      if (tid < s) sred[tid] += sred[tid + s];
      __syncthreads();
    }
    if (tid == 0) srep[b] = sred[0] - (float)K_;
    __syncthreads();
  }

  // Reg: sqrt(|E|^2) summed per b.
  sred[tid] = (tid < B_ * K_) ? sqrtf(fmaxf(ws[WS_E2 + tid], 0.0f)) : 0.0f;
  __syncthreads();
  if (tid < B_) {
    float s = 0.0f;
    for (int k = 0; k < K_; ++k) s += sred[tid * K_ + k];
    sreg[tid] = s;
  }

  // Attract per-b sums.
  if (tid < B_ * K_) {
    float v = ssum[tid] / fmaxf(scnt[tid] - 1.0f, 1.0f);
    for (int off = 1; off < K_; off <<= 1) v += __shfl_xor(v, off, 64);
    if ((tid & 15) == 0) ssa[tid >> 4] = v;
  }
  __syncthreads();

  if (tid == 0) {
    float att = 0.0f, rep = 0.0f, reg = 0.0f;
    for (int b = 0; b < B_; ++b) {
      att = (att + ssa[b]) / (float)K_;
      rep = (rep + srep[b]) / (float)(K_ * (K_ - 1));
      reg = (reg + sreg[b]) / (float)K_;
    }
    out[0] = att + rep + 0.001f * reg;  // ALPHA=BETA=1, GAMMA=0.001
    out[1] = att;
    out[2] = rep;
  }
}

extern "C" void kernel_launch(void* const* d_in, const int* in_sizes, int n_in,
                              void* d_out, int out_size, void* d_ws, size_t ws_size,
                              hipStream_t stream) {
  const float* outp = (const float*)d_in[0];
  const int* target = (const int*)d_in[1];
  const int* centers = (const int*)d_in[2];
  float* ws = (float*)d_ws;
  float* out = (float*)d_out;

  setup_kernel<<<dim3(B_, K_), 64, 0, stream>>>(outp, target, centers, ws);
  attract_kernel<<<dim3(NB2_, B_), 256, 0, stream>>>(outp, target, ws);
  final_kernel<<<1, 256, 0, stream>>>(ws, out);
}